// Round 11
// baseline (77.457 us; speedup 1.0000x reference)
//
#include <hip/hip_runtime.h>

typedef short s16x8 __attribute__((ext_vector_type(8)));
typedef float f32x4_t __attribute__((ext_vector_type(4)));

#define VOL 98
#define VPAD 112
#define CH 128
#define NWV 7
#define NTH (NWV * 64)
#define MASKNEG -1e9f

struct Smem {
  unsigned short bufA[VPAD * CH];   // 28672 B: xn (LN out) -> K; stride 256B swz
  unsigned short vt[CH * CH];       // 32768 B: V^T [d][token]; stride 256B swz
  unsigned int catbits[27][4];      // 432 B: bit j of catbits[c] => token j has category c
  int cat[VPAD];
  int gidx[VPAD];
};

__device__ __forceinline__ unsigned short f2bf(float f) {
  unsigned int u = __float_as_uint(f);
  unsigned int r = u + 0x7FFFu + ((u >> 16) & 1u);
  return (unsigned short)(r >> 16);
}
// packed f32x2 -> bf16x2, round-half-up + v_perm_b32 pack (3 VALU, no inline
// asm; the inline-asm cvt_pk variant NaN'd in R3/R4/R7 and is banned).
__device__ __forceinline__ unsigned int pk2(float a, float b) {
#if __has_builtin(__builtin_amdgcn_perm)
  return __builtin_amdgcn_perm(__float_as_uint(b) + 0x8000u,
                               __float_as_uint(a) + 0x8000u,
                               0x07060302u);
#else
  return (unsigned int)f2bf(a) | ((unsigned int)f2bf(b) << 16);
#endif
}
__device__ __forceinline__ int swz(int row, int colEl, int strideB) {
  return (row * strideB + colEl * 2) ^ ((row & 7) << 4);
}
__device__ __forceinline__ s16x8 ldsRd(const unsigned short* buf, int row, int colEl, int strideB) {
  return *(const s16x8*)((const char*)buf + swz(row, colEl, strideB));
}
__device__ __forceinline__ void ldsWr64(unsigned short* buf, int row, int colEl, int strideB,
                                        unsigned int lo, unsigned int hi) {
  unsigned long long v = (unsigned long long)lo | ((unsigned long long)hi << 32);
  *(unsigned long long*)((char*)buf + swz(row, colEl, strideB)) = v;
}
__device__ __forceinline__ void ldsWr128(unsigned short* buf, int row, int colEl, int strideB, uint4 v) {
  *(uint4*)((char*)buf + swz(row, colEl, strideB)) = v;
}
__device__ __forceinline__ s16x8 u4cast(unsigned a, unsigned b, unsigned c, unsigned d) {
  union { uint4 u; s16x8 v; } cv;
  cv.u = make_uint4(a, b, c, d);
  return cv.v;
}

// ---------------- weight prepack: fp32 -> bf16 fragments (exact RNE) ----------------
// Q columns (global col < 128) pre-scaled by hd^-0.5 * log2e.
__global__ void prepack_weights(const float* __restrict__ wqkv,
                                const float* __restrict__ wproj,
                                unsigned short* __restrict__ dst) {
  const float QSCALE = (float)(0.17677669529663687 * 1.4426950408889634);
  int lane = threadIdx.x;
  int blk = blockIdx.x;
  if (blk < 96) {
    int ct = blk >> 2, ks = blk & 3;
    int r0 = ks * 32 + ((lane >> 4) << 3);
    int col = ct * 16 + (lane & 15);
    float scl = (ct < 8) ? QSCALE : 1.0f;
    unsigned short* d = dst + (((size_t)(ct * 4 + ks) * 64 + lane) * 8);
#pragma unroll
    for (int j = 0; j < 8; ++j) d[j] = f2bf(wqkv[(size_t)(r0 + j) * 384 + col] * scl);
  } else {
    int bb = blk - 96;
    int ct = bb >> 2, ks = bb & 3;
    int r0 = ks * 32 + ((lane >> 4) << 3);
    int col = ct * 16 + (lane & 15);
    unsigned short* d = dst + 49152 + (((size_t)(ct * 4 + ks) * 64 + lane) * 8);
#pragma unroll
    for (int j = 0; j < 8; ++j) d[j] = f2bf(wproj[(size_t)(r0 + j) * 128 + col]);
  }
}

// ---------------- fused kernel: one block per cuboid, 7 waves ----------------
__global__ __launch_bounds__(NTH, 4) void fused_cuboid_attn(
    const float* __restrict__ x, const float* __restrict__ gamma,
    const float* __restrict__ beta, const float* __restrict__ bproj,
    const unsigned short* __restrict__ wfrag, float* __restrict__ out) {
  __shared__ Smem s;
  const int tid = threadIdx.x;
  const int lane = tid & 63;
  const int itw = tid >> 6;          // wave id == row-tile id (0..6)
  const int l15 = lane & 15;
  const int lg = lane >> 4;
  const int lg4 = lg * 4;
  const int lg8 = lg * 8;
  const int bid = blockIdx.x;
  const int b = bid >> 9;
  const int n = bid & 511;
  const int nt = n >> 6, nh = (n >> 3) & 7, nw = n & 7;
  // cross-lg relayout constants (used for Q frag, P frag, proj O frag)
  const int srcA = (2 * (lg & 1)) * 16 + l15;
  const int srcB = (2 * (lg & 1) + 1) * 16 + l15;
  const bool hiT = (lg >> 1) != 0;

  // phase 1a: issue ALL x loads for this thread's LN tokens up front
  const int grp = tid >> 4;
  const int l = tid & 15;
  float4 xv[4][2];
  int giv[4], catv[4];
#pragma unroll
  for (int it2 = 0; it2 < 4; ++it2) {
    int i = grp + it2 * 28;
    if (i < VOL) {
      int dt = (i >= 49) ? 1 : 0;
      int rem = i - dt * 49;
      int dh = (rem * 37) >> 8;
      int dw = rem - dh * 7;
      int t = nt * 2 + dt, h = nh * 7 + dh, w = nw * 7 + dw;
      int ts = (t + 1) & 15;
      int hs = h + 3; if (hs >= 56) hs -= 56;
      int ws2 = w + 3; if (ws2 >= 56) ws2 -= 56;
      int gi = ((b * 16 + ts) * 56 + hs) * 56 + ws2;
      const float* xp = x + (size_t)gi * CH + l * 8;
      xv[it2][0] = *(const float4*)(xp);
      xv[it2][1] = *(const float4*)(xp + 4);
      giv[it2] = gi;
      int tc = (t < 14) ? 0 : ((t < 15) ? 1 : 2);
      int hc = (h < 49) ? 0 : ((h < 53) ? 1 : 2);
      int wc = (w < 49) ? 0 : ((w < 53) ? 1 : 2);
      catv[it2] = tc * 9 + hc * 3 + wc;
    }
  }

  // phase 0: zero vt (fully: swizzle scatters unwritten token-cols 112..127),
  // bufA pad rows 98..111 (-> zero Q/K/V pads via GEMM), catbits, cat pads.
  {
    uint4 z = make_uint4(0, 0, 0, 0);
    uint4* pv = (uint4*)s.vt;
    for (int i = tid; i < 2048; i += NTH) pv[i] = z;
    if (tid < 224) ((uint4*)(s.bufA + 98 * CH))[tid] = z;
    if (tid < 27) ((uint4*)s.catbits)[tid] = z;
    if (tid >= NTH - (VPAD - VOL)) s.cat[VOL + tid - (NTH - (VPAD - VOL))] = -1;
  }
  __syncthreads();   // barrier 1 of 3

  // phase 1b: LayerNorm into bufA (as xn), one token per 16-lane group + tables
  {
    const float4 g0 = *(const float4*)(gamma + l * 8);
    const float4 g1 = *(const float4*)(gamma + l * 8 + 4);
    const float4 be0 = *(const float4*)(beta + l * 8);
    const float4 be1 = *(const float4*)(beta + l * 8 + 4);
#pragma unroll
    for (int it2 = 0; it2 < 4; ++it2) {
      int i = grp + it2 * 28;
      if (i < VOL) {
        float4 v0 = xv[it2][0];
        float4 v1 = xv[it2][1];
        float sum = v0.x + v0.y + v0.z + v0.w + v1.x + v1.y + v1.z + v1.w;
        float ssq = v0.x * v0.x + v0.y * v0.y + v0.z * v0.z + v0.w * v0.w +
                    v1.x * v1.x + v1.y * v1.y + v1.z * v1.z + v1.w * v1.w;
#pragma unroll
        for (int d = 1; d < 16; d <<= 1) {
          sum += __shfl_xor(sum, d);
          ssq += __shfl_xor(ssq, d);
        }
        float mean = sum * (1.0f / 128.0f);
        float var = ssq * (1.0f / 128.0f) - mean * mean;
        float rstd = rsqrtf(var + 1e-5f);
        uint4 pkv;
        pkv.x = pk2((v0.x - mean) * rstd * g0.x + be0.x, (v0.y - mean) * rstd * g0.y + be0.y);
        pkv.y = pk2((v0.z - mean) * rstd * g0.z + be0.z, (v0.w - mean) * rstd * g0.w + be0.w);
        pkv.z = pk2((v1.x - mean) * rstd * g1.x + be1.x, (v1.y - mean) * rstd * g1.y + be1.y);
        pkv.w = pk2((v1.z - mean) * rstd * g1.z + be1.z, (v1.w - mean) * rstd * g1.w + be1.w);
        ldsWr128(s.bufA, i, l * 8, 256, pkv);
        if (l == 0) {
          s.cat[i] = catv[it2];
          s.gidx[i] = giv[it2];
          atomicOr(&s.catbits[catv[it2]][i >> 5], 1u << (i & 31));
        }
      }
    }
  }
  __syncthreads();   // barrier 2 of 3

  // phase 2: load own-row A-frags (xn), then QKV GEMM — NO barrier needed:
  // each wave's K writes touch only its OWN rows (itw*16..+15), the same rows
  // its xf reads; all 32 Q-MFMAs consume xf before the first K write. The
  // compile-time fence stops TBAA-based hoisting of the u64* writes above the
  // short8* reads (the R3/R4 lesson).
  s16x8 xf[4];
#pragma unroll
  for (int ks = 0; ks < 4; ++ks) xf[ks] = ldsRd(s.bufA, itw * 16 + l15, ks * 32 + lg8, 256);
  asm volatile("" ::: "memory");

  unsigned qp[8][2];
  {
#pragma unroll
    for (int ct = 0; ct < 24; ++ct) {
      const unsigned short* wf = wfrag + ((size_t)ct * 2048 + (size_t)lane * 8);
      s16x8 wv[4];
#pragma unroll
      for (int ks = 0; ks < 4; ++ks) wv[ks] = *(const s16x8*)(wf + ks * 512);
      f32x4_t acc = {0.f, 0.f, 0.f, 0.f};
      if (ct < 16) {
#pragma unroll
        for (int ks = 0; ks < 4; ++ks)
          acc = __builtin_amdgcn_mfma_f32_16x16x32_bf16(wv[ks], xf[ks], acc, 0, 0, 0);
        if (ct < 8) {   // Q pre-scaled in prepack
          qp[ct][0] = pk2(acc[0], acc[1]);
          qp[ct][1] = pk2(acc[2], acc[3]);
        } else {
          ldsWr64(s.bufA, itw * 16 + l15, (ct - 8) * 16 + lg4, 256,
                  pk2(acc[0], acc[1]), pk2(acc[2], acc[3]));
        }
      } else {
#pragma unroll
        for (int ks = 0; ks < 4; ++ks)
          acc = __builtin_amdgcn_mfma_f32_16x16x32_bf16(xf[ks], wv[ks], acc, 0, 0, 0);
        ldsWr64(s.vt, (ct - 16) * 16 + l15, itw * 16 + lg4, 256,
                pk2(acc[0], acc[1]), pk2(acc[2], acc[3]));
      }
    }
  }
  __syncthreads();   // barrier 3 of 3: K + V^T complete block-wide

  // phase 3: attention, all 4 heads per wave. S^T = mfma(K, Q, C=mask);
  // lane owns query q = itw*16+l15, keys j = jt*16+lg4+r. O stays in regs.
  // No max subtraction: scores bounded (|s| << 30), masked -> exp2(-1e9)=0.
  unsigned oreg[4][4];
  {
    const int q = itw * 16 + l15;
    int cq = s.cat[q]; if (cq < 0) cq = 0;
    const uint4 mwv = *(const uint4*)&s.catbits[cq][0];
    f32x4_t cm[7];
#pragma unroll
    for (int jt = 0; jt < 7; ++jt) {
      unsigned mword = ((jt >> 1) == 0) ? mwv.x : ((jt >> 1) == 1) ? mwv.y
                      : ((jt >> 1) == 2) ? mwv.z : mwv.w;
#pragma unroll
      for (int r = 0; r < 4; ++r)
        cm[jt][r] = ((mword >> ((jt & 1) * 16 + lg4 + r)) & 1u) ? 0.f : MASKNEG;
    }
#pragma unroll
    for (int hh = 0; hh < 4; ++hh) {
      // qa fragment from Q registers via cross-lg shuffles (same l15 column)
      unsigned a0 = __shfl(qp[2 * hh][0], srcA), b0 = __shfl(qp[2 * hh + 1][0], srcA);
      unsigned a1 = __shfl(qp[2 * hh][1], srcA), b1 = __shfl(qp[2 * hh + 1][1], srcA);
      unsigned a2 = __shfl(qp[2 * hh][0], srcB), b2 = __shfl(qp[2 * hh + 1][0], srcB);
      unsigned a3 = __shfl(qp[2 * hh][1], srcB), b3 = __shfl(qp[2 * hh + 1][1], srcB);
      s16x8 qa = u4cast(hiT ? b0 : a0, hiT ? b1 : a1, hiT ? b2 : a2, hiT ? b3 : a3);
      f32x4_t sc[7];
#pragma unroll
      for (int jt = 0; jt < 7; ++jt) {
        s16x8 kb = ldsRd(s.bufA, jt * 16 + l15, hh * 32 + lg8, 256);
        sc[jt] = __builtin_amdgcn_mfma_f32_16x16x32_bf16(kb, qa, cm[jt], 0, 0, 0);
      }
      // p = exp2(s) (log2 domain, scale folded into prepacked Wq); row sum
      float s0 = 0.f, s1 = 0.f, s2 = 0.f, s3 = 0.f;
#pragma unroll
      for (int jt = 0; jt < 7; ++jt) {
        float p0 = exp2f(sc[jt][0]);
        float p1 = exp2f(sc[jt][1]);
        float p2 = exp2f(sc[jt][2]);
        float p3 = exp2f(sc[jt][3]);
        sc[jt][0] = p0; sc[jt][1] = p1; sc[jt][2] = p2; sc[jt][3] = p3;
        s0 += p0; s1 += p1; s2 += p2; s3 += p3;
      }
      float ssum = (s0 + s1) + (s2 + s3);
      ssum += __shfl_xor(ssum, 16);
      ssum += __shfl_xor(ssum, 32);
      float rinv = 1.0f / ssum;
      // pack P to bf16 pairs; index 7 = zero pad for the odd jt tile
      unsigned pj0[8], pj1[8];
#pragma unroll
      for (int jt = 0; jt < 7; ++jt) {
        pj0[jt] = pk2(sc[jt][0], sc[jt][1]);
        pj1[jt] = pk2(sc[jt][2], sc[jt][3]);
      }
      pj0[7] = 0; pj1[7] = 0;
      // PV: P-fragment via register shuffles (same srcA/srcB/hiT relayout as
      // qa; dest lane (l15,lg) holds P[q=l15][j=ks*32+lg*8..+7])
      f32x4_t o0 = {0.f, 0.f, 0.f, 0.f}, o1 = {0.f, 0.f, 0.f, 0.f};
#pragma unroll
      for (int ks = 0; ks < 4; ++ks) {
        unsigned wA0 = __shfl(pj0[2 * ks], srcA), wB0 = __shfl(pj0[2 * ks + 1], srcA);
        unsigned wA1 = __shfl(pj1[2 * ks], srcA), wB1 = __shfl(pj1[2 * ks + 1], srcA);
        unsigned wA2 = __shfl(pj0[2 * ks], srcB), wB2 = __shfl(pj0[2 * ks + 1], srcB);
        unsigned wA3 = __shfl(pj1[2 * ks], srcB), wB3 = __shfl(pj1[2 * ks + 1], srcB);
        s16x8 pa = u4cast(hiT ? wB0 : wA0, hiT ? wB1 : wA1, hiT ? wB2 : wA2, hiT ? wB3 : wA3);
        s16x8 v0 = ldsRd(s.vt, hh * 32 + l15, ks * 32 + lg8, 256);
        s16x8 v1 = ldsRd(s.vt, hh * 32 + 16 + l15, ks * 32 + lg8, 256);
        o0 = __builtin_amdgcn_mfma_f32_16x16x32_bf16(v0, pa, o0, 0, 0, 0);
        o1 = __builtin_amdgcn_mfma_f32_16x16x32_bf16(v1, pa, o1, 0, 0, 0);
      }
      oreg[hh][0] = pk2(o0[0] * rinv, o0[1] * rinv);
      oreg[hh][1] = pk2(o0[2] * rinv, o0[3] * rinv);
      oreg[hh][2] = pk2(o1[0] * rinv, o1[1] * rinv);
      oreg[hh][3] = pk2(o1[2] * rinv, o1[3] * rinv);
    }
  }

  // phase 4: proj A-frags straight from oreg via cross-lg shuffles (no LDS
  // round trip, no barriers; gidx was written before barrier 2).
  {
    s16x8 of[4];
#pragma unroll
    for (int hh = 0; hh < 4; ++hh) {
      unsigned a0 = __shfl(oreg[hh][0], srcA), a2 = __shfl(oreg[hh][2], srcA);
      unsigned a1 = __shfl(oreg[hh][1], srcA), a3 = __shfl(oreg[hh][3], srcA);
      unsigned c0 = __shfl(oreg[hh][0], srcB), c2 = __shfl(oreg[hh][2], srcB);
      unsigned c1 = __shfl(oreg[hh][1], srcB), c3 = __shfl(oreg[hh][3], srcB);
      of[hh] = u4cast(hiT ? a2 : a0, hiT ? a3 : a1, hiT ? c2 : c0, hiT ? c3 : c1);
    }
    const unsigned short* wp = wfrag + 49152;
    const int row = itw * 16 + l15;
    const bool valid = row < VOL;
    const size_t gbase = valid ? (size_t)s.gidx[row] * CH : 0;
#pragma unroll
    for (int ct = 0; ct < 8; ++ct) {
      const unsigned short* wf = wp + ((size_t)ct * 2048 + (size_t)lane * 8);
      float4 b4 = *(const float4*)(bproj + ct * 16 + lg4);
      f32x4_t acc = {b4.x, b4.y, b4.z, b4.w};
#pragma unroll
      for (int ks = 0; ks < 4; ++ks) {
        s16x8 wv = *(const s16x8*)(wf + ks * 512);
        acc = __builtin_amdgcn_mfma_f32_16x16x32_bf16(wv, of[ks], acc, 0, 0, 0);
      }
      if (valid) {
        float4 res;
        res.x = acc[0]; res.y = acc[1]; res.z = acc[2]; res.w = acc[3];
        *(float4*)(out + gbase + ct * 16 + lg4) = res;
      }
    }
  }
}

extern "C" void kernel_launch(void* const* d_in, const int* in_sizes, int n_in,
                              void* d_out, int out_size, void* d_ws, size_t ws_size,
                              hipStream_t stream) {
  const float* x = (const float*)d_in[0];
  const float* gamma = (const float*)d_in[1];
  const float* beta = (const float*)d_in[2];
  const float* wqkv = (const float*)d_in[3];
  const float* wproj = (const float*)d_in[4];
  const float* bproj = (const float*)d_in[5];
  float* out = (float*)d_out;
  unsigned short* wsf = (unsigned short*)d_ws;
  (void)in_sizes; (void)n_in; (void)out_size; (void)ws_size;

  prepack_weights<<<128, 64, 0, stream>>>(wqkv, wproj, wsf);
  fused_cuboid_attn<<<1024, NTH, 0, stream>>>(x, gamma, beta, bproj, wsf, out);
}

// Round 12
// 69.495 us; speedup vs baseline: 1.1146x; 1.1146x over previous
//
#include <hip/hip_runtime.h>

typedef short s16x8 __attribute__((ext_vector_type(8)));
typedef float f32x4_t __attribute__((ext_vector_type(4)));

#define VOL 98
#define VPAD 112
#define CH 128
#define NWV 7
#define NTH (NWV * 64)
#define MASKNEG -1e9f

struct Smem {
  unsigned short bufA[VPAD * CH];   // 28672 B: xn (LN out) -> K; stride 256B swz
  unsigned short vt[CH * CH];       // 32768 B: V^T [d][token]; stride 256B swz
  unsigned short pst[NWV][512];     // 7168 B: per-wave P staging [q16][j32]; stride 64B swz
  unsigned int catbits[27][4];      // 432 B: bit j of catbits[c] => token j has category c
  int cat[VPAD];
  int gidx[VPAD];
};

__device__ __forceinline__ unsigned short f2bf(float f) {
  unsigned int u = __float_as_uint(f);
  unsigned int r = u + 0x7FFFu + ((u >> 16) & 1u);
  return (unsigned short)(r >> 16);
}
// packed f32x2 -> bf16x2, round-half-up + v_perm_b32 pack (3 VALU, no inline
// asm; the inline-asm cvt_pk variant NaN'd in R3/R4/R7 and is banned).
__device__ __forceinline__ unsigned int pk2(float a, float b) {
#if __has_builtin(__builtin_amdgcn_perm)
  return __builtin_amdgcn_perm(__float_as_uint(b) + 0x8000u,
                               __float_as_uint(a) + 0x8000u,
                               0x07060302u);
#else
  return (unsigned int)f2bf(a) | ((unsigned int)f2bf(b) << 16);
#endif
}
__device__ __forceinline__ int swz(int row, int colEl, int strideB) {
  return (row * strideB + colEl * 2) ^ ((row & 7) << 4);
}
__device__ __forceinline__ s16x8 ldsRd(const unsigned short* buf, int row, int colEl, int strideB) {
  return *(const s16x8*)((const char*)buf + swz(row, colEl, strideB));
}
__device__ __forceinline__ void ldsWr64(unsigned short* buf, int row, int colEl, int strideB,
                                        unsigned int lo, unsigned int hi) {
  unsigned long long v = (unsigned long long)lo | ((unsigned long long)hi << 32);
  *(unsigned long long*)((char*)buf + swz(row, colEl, strideB)) = v;
}
__device__ __forceinline__ void ldsWr128(unsigned short* buf, int row, int colEl, int strideB, uint4 v) {
  *(uint4*)((char*)buf + swz(row, colEl, strideB)) = v;
}
__device__ __forceinline__ s16x8 u4cast(unsigned a, unsigned b, unsigned c, unsigned d) {
  union { uint4 u; s16x8 v; } cv;
  cv.u = make_uint4(a, b, c, d);
  return cv.v;
}

// ---------------- weight prepack: fp32 -> bf16 fragments (exact RNE) ----------------
// Q columns (global col < 128) pre-scaled by hd^-0.5 * log2e.
__global__ void prepack_weights(const float* __restrict__ wqkv,
                                const float* __restrict__ wproj,
                                unsigned short* __restrict__ dst) {
  const float QSCALE = (float)(0.17677669529663687 * 1.4426950408889634);
  int lane = threadIdx.x;
  int blk = blockIdx.x;
  if (blk < 96) {
    int ct = blk >> 2, ks = blk & 3;
    int r0 = ks * 32 + ((lane >> 4) << 3);
    int col = ct * 16 + (lane & 15);
    float scl = (ct < 8) ? QSCALE : 1.0f;
    unsigned short* d = dst + (((size_t)(ct * 4 + ks) * 64 + lane) * 8);
#pragma unroll
    for (int j = 0; j < 8; ++j) d[j] = f2bf(wqkv[(size_t)(r0 + j) * 384 + col] * scl);
  } else {
    int bb = blk - 96;
    int ct = bb >> 2, ks = bb & 3;
    int r0 = ks * 32 + ((lane >> 4) << 3);
    int col = ct * 16 + (lane & 15);
    unsigned short* d = dst + 49152 + (((size_t)(ct * 4 + ks) * 64 + lane) * 8);
#pragma unroll
    for (int j = 0; j < 8; ++j) d[j] = f2bf(wproj[(size_t)(r0 + j) * 128 + col]);
  }
}

// ---------------- fused kernel: one block per cuboid, 7 waves ----------------
__global__ __launch_bounds__(NTH, 4) void fused_cuboid_attn(
    const float* __restrict__ x, const float* __restrict__ gamma,
    const float* __restrict__ beta, const float* __restrict__ bproj,
    const unsigned short* __restrict__ wfrag, float* __restrict__ out) {
  __shared__ Smem s;
  const int tid = threadIdx.x;
  const int lane = tid & 63;
  const int itw = tid >> 6;          // wave id == row-tile id (0..6)
  const int l15 = lane & 15;
  const int lg = lane >> 4;
  const int lg4 = lg * 4;
  const int lg8 = lg * 8;
  const int bid = blockIdx.x;
  const int b = bid >> 9;
  const int n = bid & 511;
  const int nt = n >> 6, nh = (n >> 3) & 7, nw = n & 7;
  // cross-lg relayout constants (used for Q frag and proj O frag)
  const int srcA = (2 * (lg & 1)) * 16 + l15;
  const int srcB = (2 * (lg & 1) + 1) * 16 + l15;
  const bool hiT = (lg >> 1) != 0;

  // phase 1a: issue ALL x loads for this thread's LN tokens up front
  const int grp = tid >> 4;
  const int l = tid & 15;
  float4 xv[4][2];
  int giv[4], catv[4];
#pragma unroll
  for (int it2 = 0; it2 < 4; ++it2) {
    int i = grp + it2 * 28;
    if (i < VOL) {
      int dt = (i >= 49) ? 1 : 0;
      int rem = i - dt * 49;
      int dh = (rem * 37) >> 8;
      int dw = rem - dh * 7;
      int t = nt * 2 + dt, h = nh * 7 + dh, w = nw * 7 + dw;
      int ts = (t + 1) & 15;
      int hs = h + 3; if (hs >= 56) hs -= 56;
      int ws2 = w + 3; if (ws2 >= 56) ws2 -= 56;
      int gi = ((b * 16 + ts) * 56 + hs) * 56 + ws2;
      const float* xp = x + (size_t)gi * CH + l * 8;
      xv[it2][0] = *(const float4*)(xp);
      xv[it2][1] = *(const float4*)(xp + 4);
      giv[it2] = gi;
      int tc = (t < 14) ? 0 : ((t < 15) ? 1 : 2);
      int hc = (h < 49) ? 0 : ((h < 53) ? 1 : 2);
      int wc = (w < 49) ? 0 : ((w < 53) ? 1 : 2);
      catv[it2] = tc * 9 + hc * 3 + wc;
    }
  }

  // phase 0: zero vt (fully: swizzle scatters unwritten token-cols 112..127),
  // bufA pad rows 98..111 (-> zero Q/K/V pads via GEMM), catbits, cat pads.
  {
    uint4 z = make_uint4(0, 0, 0, 0);
    uint4* pv = (uint4*)s.vt;
    for (int i = tid; i < 2048; i += NTH) pv[i] = z;
    if (tid < 224) ((uint4*)(s.bufA + 98 * CH))[tid] = z;
    if (tid < 27) ((uint4*)s.catbits)[tid] = z;
    if (tid >= NTH - (VPAD - VOL)) s.cat[VOL + tid - (NTH - (VPAD - VOL))] = -1;
  }
  __syncthreads();   // barrier 1 of 3

  // phase 1b: LayerNorm into bufA (as xn), one token per 16-lane group + tables
  {
    const float4 g0 = *(const float4*)(gamma + l * 8);
    const float4 g1 = *(const float4*)(gamma + l * 8 + 4);
    const float4 be0 = *(const float4*)(beta + l * 8);
    const float4 be1 = *(const float4*)(beta + l * 8 + 4);
#pragma unroll
    for (int it2 = 0; it2 < 4; ++it2) {
      int i = grp + it2 * 28;
      if (i < VOL) {
        float4 v0 = xv[it2][0];
        float4 v1 = xv[it2][1];
        float sum = v0.x + v0.y + v0.z + v0.w + v1.x + v1.y + v1.z + v1.w;
        float ssq = v0.x * v0.x + v0.y * v0.y + v0.z * v0.z + v0.w * v0.w +
                    v1.x * v1.x + v1.y * v1.y + v1.z * v1.z + v1.w * v1.w;
#pragma unroll
        for (int d = 1; d < 16; d <<= 1) {
          sum += __shfl_xor(sum, d);
          ssq += __shfl_xor(ssq, d);
        }
        float mean = sum * (1.0f / 128.0f);
        float var = ssq * (1.0f / 128.0f) - mean * mean;
        float rstd = rsqrtf(var + 1e-5f);
        uint4 pkv;
        pkv.x = pk2((v0.x - mean) * rstd * g0.x + be0.x, (v0.y - mean) * rstd * g0.y + be0.y);
        pkv.y = pk2((v0.z - mean) * rstd * g0.z + be0.z, (v0.w - mean) * rstd * g0.w + be0.w);
        pkv.z = pk2((v1.x - mean) * rstd * g1.x + be1.x, (v1.y - mean) * rstd * g1.y + be1.y);
        pkv.w = pk2((v1.z - mean) * rstd * g1.z + be1.z, (v1.w - mean) * rstd * g1.w + be1.w);
        ldsWr128(s.bufA, i, l * 8, 256, pkv);
        if (l == 0) {
          s.cat[i] = catv[it2];
          s.gidx[i] = giv[it2];
          atomicOr(&s.catbits[catv[it2]][i >> 5], 1u << (i & 31));
        }
      }
    }
  }
  __syncthreads();   // barrier 2 of 3

  // phase 2: load own-row A-frags (xn), then QKV GEMM — no barrier needed:
  // each wave's K writes touch only its OWN rows (itw*16..+15), the same rows
  // its xf reads. Compile-time fence stops TBAA-based hoisting of the u64*
  // writes above the short8* reads (the R3/R4 lesson).
  s16x8 xf[4];
#pragma unroll
  for (int ks = 0; ks < 4; ++ks) xf[ks] = ldsRd(s.bufA, itw * 16 + l15, ks * 32 + lg8, 256);
  asm volatile("" ::: "memory");

  unsigned qp[8][2];
  {
#pragma unroll
    for (int ct = 0; ct < 24; ++ct) {
      const unsigned short* wf = wfrag + ((size_t)ct * 2048 + (size_t)lane * 8);
      s16x8 wv[4];
#pragma unroll
      for (int ks = 0; ks < 4; ++ks) wv[ks] = *(const s16x8*)(wf + ks * 512);
      f32x4_t acc = {0.f, 0.f, 0.f, 0.f};
      if (ct < 16) {
#pragma unroll
        for (int ks = 0; ks < 4; ++ks)
          acc = __builtin_amdgcn_mfma_f32_16x16x32_bf16(wv[ks], xf[ks], acc, 0, 0, 0);
        if (ct < 8) {   // Q pre-scaled in prepack
          qp[ct][0] = pk2(acc[0], acc[1]);
          qp[ct][1] = pk2(acc[2], acc[3]);
        } else {
          ldsWr64(s.bufA, itw * 16 + l15, (ct - 8) * 16 + lg4, 256,
                  pk2(acc[0], acc[1]), pk2(acc[2], acc[3]));
        }
      } else {
#pragma unroll
        for (int ks = 0; ks < 4; ++ks)
          acc = __builtin_amdgcn_mfma_f32_16x16x32_bf16(xf[ks], wv[ks], acc, 0, 0, 0);
        ldsWr64(s.vt, (ct - 16) * 16 + l15, itw * 16 + lg4, 256,
                pk2(acc[0], acc[1]), pk2(acc[2], acc[3]));
      }
    }
  }
  __syncthreads();   // barrier 3 of 3: K + V^T complete block-wide

  // phase 3: attention, all 4 heads per wave. S^T = mfma(K, Q, C=mask);
  // lane owns query q = itw*16+l15, keys j = jt*16+lg4+r. O stays in regs.
  // No max subtraction (R11-validated): scores bounded, masked -> exp2(-1e9)=0.
  unsigned oreg[4][4];
  {
    unsigned short* ps = s.pst[itw];
    const int q = itw * 16 + l15;
    int cq = s.cat[q]; if (cq < 0) cq = 0;
    const uint4 mwv = *(const uint4*)&s.catbits[cq][0];
    f32x4_t cm[7];
#pragma unroll
    for (int jt = 0; jt < 7; ++jt) {
      unsigned mword = ((jt >> 1) == 0) ? mwv.x : ((jt >> 1) == 1) ? mwv.y
                      : ((jt >> 1) == 2) ? mwv.z : mwv.w;
#pragma unroll
      for (int r = 0; r < 4; ++r)
        cm[jt][r] = ((mword >> ((jt & 1) * 16 + lg4 + r)) & 1u) ? 0.f : MASKNEG;
    }
#pragma unroll
    for (int hh = 0; hh < 4; ++hh) {
      // qa fragment from Q registers via cross-lg shuffles (same l15 column)
      unsigned a0 = __shfl(qp[2 * hh][0], srcA), b0 = __shfl(qp[2 * hh + 1][0], srcA);
      unsigned a1 = __shfl(qp[2 * hh][1], srcA), b1 = __shfl(qp[2 * hh + 1][1], srcA);
      unsigned a2 = __shfl(qp[2 * hh][0], srcB), b2 = __shfl(qp[2 * hh + 1][0], srcB);
      unsigned a3 = __shfl(qp[2 * hh][1], srcB), b3 = __shfl(qp[2 * hh + 1][1], srcB);
      s16x8 qa = u4cast(hiT ? b0 : a0, hiT ? b1 : a1, hiT ? b2 : a2, hiT ? b3 : a3);
      f32x4_t sc[7];
#pragma unroll
      for (int jt = 0; jt < 7; ++jt) {
        s16x8 kb = ldsRd(s.bufA, jt * 16 + l15, hh * 32 + lg8, 256);
        sc[jt] = __builtin_amdgcn_mfma_f32_16x16x32_bf16(kb, qa, cm[jt], 0, 0, 0);
      }
      // p = exp2(s) (log2 domain, scale folded into prepacked Wq); row sum
      float s0 = 0.f, s1 = 0.f, s2 = 0.f, s3 = 0.f;
#pragma unroll
      for (int jt = 0; jt < 7; ++jt) {
        float p0 = exp2f(sc[jt][0]);
        float p1 = exp2f(sc[jt][1]);
        float p2 = exp2f(sc[jt][2]);
        float p3 = exp2f(sc[jt][3]);
        sc[jt][0] = p0; sc[jt][1] = p1; sc[jt][2] = p2; sc[jt][3] = p3;
        s0 += p0; s1 += p1; s2 += p2; s3 += p3;
      }
      float ssum = (s0 + s1) + (s2 + s3);
      ssum += __shfl_xor(ssum, 16);
      ssum += __shfl_xor(ssum, 32);
      float rinv = 1.0f / ssum;
      // PV per 32-key chunk via per-wave staging tile (P unnormalized)
      f32x4_t o0 = {0.f, 0.f, 0.f, 0.f}, o1 = {0.f, 0.f, 0.f, 0.f};
#pragma unroll
      for (int ks = 0; ks < 4; ++ks) {
        const int jtA = 2 * ks, jtB = 2 * ks + 1;
        ldsWr64(ps, l15, lg4, 64, pk2(sc[jtA][0], sc[jtA][1]), pk2(sc[jtA][2], sc[jtA][3]));
        unsigned pb0 = 0, pb1 = 0;
        if (jtB < 7) {
          pb0 = pk2(sc[jtB][0], sc[jtB][1]);
          pb1 = pk2(sc[jtB][2], sc[jtB][3]);
        }
        ldsWr64(ps, l15, 16 + lg4, 64, pb0, pb1);
        asm volatile("" ::: "memory");  // order pst write (u64*) vs read (short8*)
        s16x8 pa = ldsRd(ps, l15, lg8, 64);
        s16x8 v0 = ldsRd(s.vt, hh * 32 + l15, ks * 32 + lg8, 256);
        s16x8 v1 = ldsRd(s.vt, hh * 32 + 16 + l15, ks * 32 + lg8, 256);
        o0 = __builtin_amdgcn_mfma_f32_16x16x32_bf16(v0, pa, o0, 0, 0, 0);
        o1 = __builtin_amdgcn_mfma_f32_16x16x32_bf16(v1, pa, o1, 0, 0, 0);
      }
      oreg[hh][0] = pk2(o0[0] * rinv, o0[1] * rinv);
      oreg[hh][1] = pk2(o0[2] * rinv, o0[3] * rinv);
      oreg[hh][2] = pk2(o1[0] * rinv, o1[1] * rinv);
      oreg[hh][3] = pk2(o1[2] * rinv, o1[3] * rinv);
    }
  }

  // phase 4: proj A-frags straight from oreg via cross-lg shuffles (no LDS
  // round trip, no barriers; gidx was written before barrier 2).
  {
    s16x8 of[4];
#pragma unroll
    for (int hh = 0; hh < 4; ++hh) {
      unsigned a0 = __shfl(oreg[hh][0], srcA), a2 = __shfl(oreg[hh][2], srcA);
      unsigned a1 = __shfl(oreg[hh][1], srcA), a3 = __shfl(oreg[hh][3], srcA);
      unsigned c0 = __shfl(oreg[hh][0], srcB), c2 = __shfl(oreg[hh][2], srcB);
      unsigned c1 = __shfl(oreg[hh][1], srcB), c3 = __shfl(oreg[hh][3], srcB);
      of[hh] = u4cast(hiT ? a2 : a0, hiT ? a3 : a1, hiT ? c2 : c0, hiT ? c3 : c1);
    }
    const unsigned short* wp = wfrag + 49152;
    const int row = itw * 16 + l15;
    const bool valid = row < VOL;
    const size_t gbase = valid ? (size_t)s.gidx[row] * CH : 0;
#pragma unroll
    for (int ct = 0; ct < 8; ++ct) {
      const unsigned short* wf = wp + ((size_t)ct * 2048 + (size_t)lane * 8);
      float4 b4 = *(const float4*)(bproj + ct * 16 + lg4);
      f32x4_t acc = {b4.x, b4.y, b4.z, b4.w};
#pragma unroll
      for (int ks = 0; ks < 4; ++ks) {
        s16x8 wv = *(const s16x8*)(wf + ks * 512);
        acc = __builtin_amdgcn_mfma_f32_16x16x32_bf16(wv, of[ks], acc, 0, 0, 0);
      }
      if (valid) {
        float4 res;
        res.x = acc[0]; res.y = acc[1]; res.z = acc[2]; res.w = acc[3];
        *(float4*)(out + gbase + ct * 16 + lg4) = res;
      }
    }
  }
}

extern "C" void kernel_launch(void* const* d_in, const int* in_sizes, int n_in,
                              void* d_out, int out_size, void* d_ws, size_t ws_size,
                              hipStream_t stream) {
  const float* x = (const float*)d_in[0];
  const float* gamma = (const float*)d_in[1];
  const float* beta = (const float*)d_in[2];
  const float* wqkv = (const float*)d_in[3];
  const float* wproj = (const float*)d_in[4];
  const float* bproj = (const float*)d_in[5];
  float* out = (float*)d_out;
  unsigned short* wsf = (unsigned short*)d_ws;
  (void)in_sizes; (void)n_in; (void)out_size; (void)ws_size;

  prepack_weights<<<128, 64, 0, stream>>>(wqkv, wproj, wsf);
  fused_cuboid_attn<<<1024, NTH, 0, stream>>>(x, gamma, beta, bproj, wsf, out);
}